// Round 19
// baseline (45.661 us; speedup 1.0000x reference)
//
#include <hip/hip_runtime.h>

// SimpleHybridModel via MFMA, all-transposed chaining:
//  conv1d(k=3,SAME,relu) -> SimpleRNN(16,tanh) -> dense(8,relu) -> dense(1)
//
// R19 = R18 (39.7us, single-wave blocks, 14 blocks/CU = 448 resident elems)
// + intra-wave async 2-tile pipeline (T14 pattern):
//   stage tile0 -> issue tile1 loads -> COMPUTE tile0 (tile1 HBM latency
//   hides under ~2.5k cy of compute) -> lgkmcnt fence (same-wave LDS order,
//   rule #18 pin) -> convert+write tile1 -> compute tile1.
// Single LDS buffer (10784B, 14 blocks/CU unchanged); grid 4096 (16/CU).
// Rationale: wave lifetime ~41k cy vs ~3k issue -> memory-dominated; per-CU
// HBM share for x is ~23us of the 39.7 -> the lever is overlap, not issue.
// Fragment setup amortized 2x. VGPR ~200 -> __launch_bounds__(64,2).
// Retained from R18: 21-slot f16 element layout (slot0 pad (0..0,1.0h);
// slot l+g read as one aligned ds_read_b128; elem e row-20 read = elem
// e+1's pad; dummy 1.0 at half 7 feeds the k=31 conv-bias tap; 2 guard
// slots), conflict-free staging writes, conv bias rides MFMA, 2*log2e
// folded into A2/AU/rnn_b, rcp+exp2 tanh, packed cvts, head via MFMA.

#define BLK 64
#define LSEQ 20
#define EPW 84              // dwords per element: 21 slots * 4
#define LOG2E2 2.8853900817779268f

typedef _Float16 f16;
typedef __fp16   fp16x2 __attribute__((ext_vector_type(2)));
typedef _Float16 f16x4 __attribute__((ext_vector_type(4)));
typedef _Float16 f16x8 __attribute__((ext_vector_type(8)));
typedef float    f32x4 __attribute__((ext_vector_type(4)));

union UB128 { uint4 q; f16x8 v; };
union UB64  { f16x4 v; fp16x2 p[2]; };
union HU    { fp16x2 p; uint u; };

__global__ __launch_bounds__(BLK, 2) void hybrid_fwd(
    const float* __restrict__ x,
    const float* __restrict__ conv_w, const float* __restrict__ conv_b,
    const float* __restrict__ rnn_w,  const float* __restrict__ rnn_u,
    const float* __restrict__ rnn_b,
    const float* __restrict__ d1_w,   const float* __restrict__ d1_b,
    const float* __restrict__ out_w,  const float* __restrict__ out_b,
    float* __restrict__ out)
{
    __shared__ __align__(16) uint xs[32 * EPW + 8];   // 10784 B

    const int lane = threadIdx.x;                 // single wave
    const int b16  = lane & 15, g = lane >> 4;
    const long BE  = (long)blockIdx.x * 64;       // block's first elem (2 tiles)

    const int e = lane & 31;                      // staged elem within tile
    const int h = lane >> 5;                      // half: rows 10h..10h+9

    // ---- weight fragments FIRST (latency overlaps tile0 staging) ----
    f16x8 A1;
    #pragma unroll
    for (int t = 0; t < 8; ++t) {
        float wv = conv_w[min(g * 7 + t, 20) * 16 + b16];
        float sel = (g < 3 && t < 7) ? wv
                  : ((g == 3 && t == 7) ? conv_b[b16] : 0.f);
        A1[t] = (f16)sel;
    }
    f16x4 A2, AU;
    f32x4 rbp;
    #pragma unroll
    for (int t = 0; t < 4; ++t) {
        A2[t]  = (f16)(LOG2E2 * rnn_w[(4 * g + t) * 16 + b16]);
        AU[t]  = (f16)(LOG2E2 * rnn_u[(4 * g + t) * 16 + b16]);
        rbp[t] = LOG2E2 * rnn_b[4 * g + t];
    }
    f16x4 A3;
    f32x4 c3;
    #pragma unroll
    for (int t = 0; t < 4; ++t) {
        int j = 4 * g + t;
        A3[t] = (f16)(b16 < 8 ? d1_w[j * 8 + b16] : 0.f);
        c3[t] = d1_b[min(j, 7)];
    }
    float ow[4];
    #pragma unroll
    for (int r = 0; r < 4; ++r)
        ow[r] = (g < 2) ? out_w[min(4 * g + r, 7)] : 0.f;
    const float ob = out_b[0];
    const f32x4 zero4 = {0.f, 0.f, 0.f, 0.f};

    // ---- pads: slot0 of each elem + 2 guard slots (static, written once) ----
    const uint4 PAD = make_uint4(0u, 0u, 0u, 0x3C000000u);
    if (h == 0) *(uint4*)(xs + e * EPW) = PAD;
    if (lane < 2) *(uint4*)(xs + 32 * EPW + 4 * lane) = PAD;

    float2 f2[35];      // staging registers (70 VGPR while in flight)

#define LOADF2(T)                                                              \
    {                                                                          \
        const float2* sp = (const float2*)(x + (BE + (T) * 32 + e) * 140 + h * 70); \
        _Pragma("unroll")                                                      \
        for (int i = 0; i < 35; ++i) f2[i] = sp[i];                            \
    }

#define WRITETILE()                                                            \
    {                                                                          \
        const float* f = (const float*)f2;                                     \
        uint* eb = xs + e * EPW;                                               \
        _Pragma("unroll")                                                      \
        for (int i = 0; i < 10; ++i) {                                         \
            HU h0, h1, h2, h3;                                                 \
            h0.p = __builtin_amdgcn_cvt_pkrtz(f[7 * i + 0], f[7 * i + 1]);     \
            h1.p = __builtin_amdgcn_cvt_pkrtz(f[7 * i + 2], f[7 * i + 3]);     \
            h2.p = __builtin_amdgcn_cvt_pkrtz(f[7 * i + 4], f[7 * i + 5]);     \
            h3.p = __builtin_amdgcn_cvt_pkrtz(f[7 * i + 6], 1.0f);             \
            uint4 val; val.x = h0.u; val.y = h1.u; val.z = h2.u; val.w = h3.u; \
            *(uint4*)(eb + 4 * (10 * h + i + 1)) = val;                        \
        }                                                                      \
    }

#define FENCE()                                                                \
    asm volatile("s_waitcnt lgkmcnt(0)" ::: "memory");                         \
    __builtin_amdgcn_sched_barrier(0);

    // read bases; chain c elem = c*16 + b16; step l: +16B
    const uint* rb0 = xs + b16 * EPW + 4 * g;
    const uint* rb1 = rb0 + 16 * EPW;

    auto compute_tile = [&](int tidx) {
        // Phase A: conv + relu, both chains, full unroll
        f16x4 B2sA[LSEQ], B2sB[LSEQ];
        #pragma unroll
        for (int l = 0; l < LSEQ; ++l) {
            UB128 B1a, B1b;
            B1a.q = *(const uint4*)(rb0 + 4 * l);
            B1b.q = *(const uint4*)(rb1 + 4 * l);
            f32x4 a1a = __builtin_amdgcn_mfma_f32_16x16x32_f16(A1, B1a.v, zero4, 0, 0, 0);
            f32x4 a1b = __builtin_amdgcn_mfma_f32_16x16x32_f16(A1, B1b.v, zero4, 0, 0, 0);
            UB64 Ba, Bb;
            Ba.p[0] = __builtin_amdgcn_cvt_pkrtz(fmaxf(a1a[0], 0.f), fmaxf(a1a[1], 0.f));
            Ba.p[1] = __builtin_amdgcn_cvt_pkrtz(fmaxf(a1a[2], 0.f), fmaxf(a1a[3], 0.f));
            Bb.p[0] = __builtin_amdgcn_cvt_pkrtz(fmaxf(a1b[0], 0.f), fmaxf(a1b[1], 0.f));
            Bb.p[1] = __builtin_amdgcn_cvt_pkrtz(fmaxf(a1b[2], 0.f), fmaxf(a1b[3], 0.f));
            B2sA[l] = Ba.v;
            B2sB[l] = Bb.v;
        }
        // Phase B: two independent serial recurrences, interleaved
        f16x4 H0 = {}, H1 = {};
        #pragma unroll
        for (int l = 0; l < LSEQ; ++l) {
            f32x4 a20 = __builtin_amdgcn_mfma_f32_16x16x16f16(A2, B2sA[l], rbp, 0, 0, 0);
            f32x4 a21 = __builtin_amdgcn_mfma_f32_16x16x16f16(A2, B2sB[l], rbp, 0, 0, 0);
            a20 = __builtin_amdgcn_mfma_f32_16x16x16f16(AU, H0, a20, 0, 0, 0);
            a21 = __builtin_amdgcn_mfma_f32_16x16x16f16(AU, H1, a21, 0, 0, 0);
            float t00 = __builtin_amdgcn_rcpf(1.f + __builtin_amdgcn_exp2f(a20[0]));
            float t01 = __builtin_amdgcn_rcpf(1.f + __builtin_amdgcn_exp2f(a20[1]));
            float t02 = __builtin_amdgcn_rcpf(1.f + __builtin_amdgcn_exp2f(a20[2]));
            float t03 = __builtin_amdgcn_rcpf(1.f + __builtin_amdgcn_exp2f(a20[3]));
            float t10 = __builtin_amdgcn_rcpf(1.f + __builtin_amdgcn_exp2f(a21[0]));
            float t11 = __builtin_amdgcn_rcpf(1.f + __builtin_amdgcn_exp2f(a21[1]));
            float t12 = __builtin_amdgcn_rcpf(1.f + __builtin_amdgcn_exp2f(a21[2]));
            float t13 = __builtin_amdgcn_rcpf(1.f + __builtin_amdgcn_exp2f(a21[3]));
            UB64 Hn0, Hn1;
            Hn0.p[0] = __builtin_amdgcn_cvt_pkrtz(fmaf(-2.f, t00, 1.f), fmaf(-2.f, t01, 1.f));
            Hn0.p[1] = __builtin_amdgcn_cvt_pkrtz(fmaf(-2.f, t02, 1.f), fmaf(-2.f, t03, 1.f));
            Hn1.p[0] = __builtin_amdgcn_cvt_pkrtz(fmaf(-2.f, t10, 1.f), fmaf(-2.f, t11, 1.f));
            Hn1.p[1] = __builtin_amdgcn_cvt_pkrtz(fmaf(-2.f, t12, 1.f), fmaf(-2.f, t13, 1.f));
            H0 = Hn0.v;
            H1 = Hn1.v;
        }
        // head via MFMA
        f32x4 a30 = __builtin_amdgcn_mfma_f32_16x16x16f16(A3, H0, c3, 0, 0, 0);
        f32x4 a31 = __builtin_amdgcn_mfma_f32_16x16x16f16(A3, H1, c3, 0, 0, 0);
        float p0 = 0.f, p1 = 0.f;
        #pragma unroll
        for (int r = 0; r < 4; ++r) {
            p0 = fmaf(fmaxf(a30[r], 0.f), ow[r], p0);
            p1 = fmaf(fmaxf(a31[r], 0.f), ow[r], p1);
        }
        p0 += __shfl_xor(p0, 16); p0 += __shfl_xor(p0, 32);
        p1 += __shfl_xor(p1, 16); p1 += __shfl_xor(p1, 32);
        if (lane < 16) {
            out[BE + tidx * 32 + b16]      = p0 + ob;
            out[BE + tidx * 32 + 16 + b16] = p1 + ob;
        }
    };

    // ---- prologue: stage tile 0 ----
    LOADF2(0);
    WRITETILE();
    FENCE();

    // ---- tile 0: issue tile-1 loads, compute under their latency ----
    LOADF2(1);
    compute_tile(0);

    // ---- write tile 1 (loads arrived under compute), then compute ----
    FENCE();            // pin: all tile-0 ds_reads complete before overwrite
    WRITETILE();
    FENCE();
    compute_tile(1);

#undef LOADF2
#undef WRITETILE
#undef FENCE
}

extern "C" void kernel_launch(void* const* d_in, const int* in_sizes, int n_in,
                              void* d_out, int out_size, void* d_ws, size_t ws_size,
                              hipStream_t stream) {
    const float* x      = (const float*)d_in[0];
    const float* conv_w = (const float*)d_in[1];
    const float* conv_b = (const float*)d_in[2];
    const float* rnn_w  = (const float*)d_in[3];
    const float* rnn_u  = (const float*)d_in[4];
    const float* rnn_b  = (const float*)d_in[5];
    const float* d1_w   = (const float*)d_in[6];
    const float* d1_b   = (const float*)d_in[7];
    const float* out_w  = (const float*)d_in[8];
    const float* out_b  = (const float*)d_in[9];
    float* out = (float*)d_out;

    const int B = out_size;                 // 262144
    const int grid = B / 64;                // 4096 blocks x 2 tiles
    hybrid_fwd<<<grid, BLK, 0, stream>>>(x, conv_w, conv_b, rnn_w, rnn_u, rnn_b,
                                         d1_w, d1_b, out_w, out_b, out);
}